// Round 3
// baseline (1401.779 us; speedup 1.0000x reference)
//
#include <hip/hip_runtime.h>
#include <cstdint>
#include <cstddef>

// ---------------------------------------------------------------------------
// QwenDoubleStreamAttention — round 6: counted-vmcnt prefetch across raw
// barriers in attn (kill the __syncthreads vmcnt(0) drain).
//   B=2, S_img=2048, S_txt=256 (S=2304), D=3072, H=24, DH=128.
// Pipeline:
//   cvt_kernel       : hidden/enc fp32 -> bf16
//   transpose_w      : W fp32 [k][n] -> bf16 [n][k]
//   gemm_bf16<true>  : MFMA qkv proj -> bf16 [B][H][S][DH]
//   rmsrope_kernel   : RMSNorm + RoPE on q,k in place (q pre-scaled by DH^-0.5)
//   transpose_v      : V [B][H][S][DH] -> Vt [B][H][DH][S]
//   attn_kernel      : 32x32x16 MFMA flash attention, swapped QK^T,
//                      in-register softmax (cvt_pk + permlane32_swap),
//                      XOR-swizzled K/Vt LDS (32 KB), defer-max,
//                      raw s_barrier + explicit lgkmcnt(0) so next-next-tile
//                      global loads stay in flight across barriers (T3/T4).
//   gemm_bf16<false> : MFMA out-proj -> d_out fp32
// Workspace: 226,492,416 B (round-1 budget, proven available).
// ---------------------------------------------------------------------------

#define D_MODEL 3072
#define NHEADS 24
#define DHEAD 128
#define S_IMGC 2048
#define S_TXTC 256
#define S_TOT 2304
#define BATCH 2
#define ATT_SCALE 0.08838834764831845f  // 128^-0.5

typedef __attribute__((ext_vector_type(8))) short short8;   // 8 bf16 = 4 VGPR
typedef __attribute__((ext_vector_type(4))) float f32x4;
typedef __attribute__((ext_vector_type(16))) float f32x16;
typedef __attribute__((ext_vector_type(4))) unsigned int uint4v;

__device__ __forceinline__ ushort f2bf(float f) {  // fp32 -> bf16 RNE
    uint u = __float_as_uint(f);
    return (ushort)((u + 0x7fffu + ((u >> 16) & 1u)) >> 16);
}

__device__ __forceinline__ uint pk_bf16(float lo, float hi) {
    uint r;
    asm("v_cvt_pk_bf16_f32 %0, %1, %2" : "=v"(r) : "v"(lo), "v"(hi));
    return r;
}

// ---------------------------------------------------------------------------
__global__ __launch_bounds__(256) void cvt_kernel(
    const float* __restrict__ src, ushort* __restrict__ dst, int n4)
{
    int i = blockIdx.x * 256 + threadIdx.x;
    if (i >= n4) return;
    float4 v = ((const float4*)src)[i];
    ushort4 o;
    o.x = f2bf(v.x); o.y = f2bf(v.y); o.z = f2bf(v.z); o.w = f2bf(v.w);
    ((ushort4*)dst)[i] = o;
}

// ---------------------------------------------------------------------------
// W fp32 [k][n] -> bf16 [n][k].  64x64 LDS tile; grid.z picks weight.
// ---------------------------------------------------------------------------
__global__ __launch_bounds__(256) void transpose_w(
    const float* __restrict__ W0, const float* __restrict__ W1,
    const float* __restrict__ W2,
    ushort* __restrict__ T0, ushort* __restrict__ T1, ushort* __restrict__ T2)
{
    __shared__ float tile[64][68];
    const int z = blockIdx.z;
    const float* __restrict__ W = (z == 0) ? W0 : (z == 1) ? W1 : W2;
    ushort* __restrict__ T      = (z == 0) ? T0 : (z == 1) ? T1 : T2;
    const int tid = threadIdx.x;
    const int k0 = blockIdx.x * 64, n0 = blockIdx.y * 64;
    const int r = tid >> 4, c4 = (tid & 15) * 4;
#pragma unroll
    for (int i = 0; i < 4; i++) {
        float4 v = *(const float4*)(W + (size_t)(k0 + r + 16 * i) * D_MODEL + n0 + c4);
        *(float4*)&tile[r + 16 * i][c4] = v;
    }
    __syncthreads();
#pragma unroll
    for (int i = 0; i < 4; i++) {
        const int nn = n0 + r + 16 * i;
        ushort4 o;
        o.x = f2bf(tile[c4 + 0][r + 16 * i]);
        o.y = f2bf(tile[c4 + 1][r + 16 * i]);
        o.z = f2bf(tile[c4 + 2][r + 16 * i]);
        o.w = f2bf(tile[c4 + 3][r + 16 * i]);
        *(ushort4*)(T + (size_t)nn * D_MODEL + k0 + c4) = o;
    }
}

// ---------------------------------------------------------------------------
// V bf16 [B][H][S][DH] -> Vt bf16 [B][H][DH][S].  64x64 tiles.
// ---------------------------------------------------------------------------
__global__ __launch_bounds__(256) void transpose_v(
    const ushort* __restrict__ v, ushort* __restrict__ vt)
{
    __shared__ ushort t[64][72];
    const int bh = blockIdx.z;
    const int s0 = blockIdx.x * 64, d0 = blockIdx.y * 64;
    const size_t base  = (size_t)bh * S_TOT * DHEAD;
    const size_t baset = (size_t)bh * DHEAD * S_TOT;
    const int tid = threadIdx.x;
#pragma unroll
    for (int i = 0; i < 2; i++) {
        int id = tid + 256 * i;
        int r = id >> 3, c = (id & 7) * 8;
        *(uint4*)&t[r][c] = *(const uint4*)(v + base + (size_t)(s0 + r) * DHEAD + d0 + c);
    }
    __syncthreads();
#pragma unroll
    for (int i = 0; i < 2; i++) {
        int id = tid + 256 * i;
        int r = id >> 3, c = (id & 7) * 8;  // r = dh_loc, c = s chunk base
        ushort tmp[8];
#pragma unroll
        for (int j = 0; j < 8; j++) tmp[j] = t[c + j][r];
        *(uint4*)(vt + baset + (size_t)(d0 + r) * S_TOT + s0 + c) = *(uint4*)tmp;
    }
}

// ---------------------------------------------------------------------------
// MFMA GEMM (round-2 structure, unchanged).
// ---------------------------------------------------------------------------
template <bool QKV_STORE>
__global__ __launch_bounds__(256) void gemm_bf16(
    const ushort* __restrict__ A, size_t A_bstride, int As_off, int rows_per_b,
    const ushort* __restrict__ B0, const ushort* __restrict__ B1,
    const ushort* __restrict__ B2,
    const float* __restrict__ bi0, const float* __restrict__ bi1,
    const float* __restrict__ bi2,
    ushort* __restrict__ Q0, ushort* __restrict__ Q1, ushort* __restrict__ Q2,
    float* __restrict__ Cf, int C_s_off)
{
    __shared__ ushort As[128 * 32];
    __shared__ ushort Bs[128 * 32];

    const int z = blockIdx.z;
    const ushort* __restrict__ Wt  = (z == 0) ? B0 : (z == 1) ? B1 : B2;
    const float* __restrict__ bias = (z == 0) ? bi0 : (z == 1) ? bi1 : bi2;
    ushort* __restrict__ Cq        = (z == 0) ? Q0 : (z == 1) ? Q1 : Q2;

    const int tid = threadIdx.x;
    const int w = tid >> 6, lane = tid & 63;
    const int m0 = blockIdx.x * 128, n0 = blockIdx.y * 128;
    const int wm = w & 1, wn = w >> 1;

    const int ar0 = w * 32 + (lane >> 2);
    const int ar1 = ar0 + 16;
    const int acol = (lane & 3) * 8;
    const int ma0 = m0 + ar0, ma1 = m0 + ar1;
    const ushort* gA0 = A + (size_t)(ma0 / rows_per_b) * A_bstride +
                        (size_t)(ma0 % rows_per_b + As_off) * D_MODEL + acol;
    const ushort* gA1 = A + (size_t)(ma1 / rows_per_b) * A_bstride +
                        (size_t)(ma1 % rows_per_b + As_off) * D_MODEL + acol;
    const ushort* gB0 = Wt + (size_t)(n0 + ar0) * D_MODEL + acol;
    const ushort* gB1 = Wt + (size_t)(n0 + ar1) * D_MODEL + acol;
    ushort* lA0 = As + (w * 32) * 32;
    ushort* lA1 = As + (w * 32 + 16) * 32;
    ushort* lB0 = Bs + (w * 32) * 32;
    ushort* lB1 = Bs + (w * 32 + 16) * 32;

    f32x4 acc[4][4];
#pragma unroll
    for (int i = 0; i < 4; i++)
#pragma unroll
        for (int j = 0; j < 4; j++) acc[i][j] = (f32x4)0.f;

    const ushort* ap = As + (wm * 64 + (lane & 15)) * 32 + (lane >> 4) * 8;
    const ushort* bp = Bs + (wn * 64 + (lane & 15)) * 32 + (lane >> 4) * 8;

    for (int k0 = 0; k0 < D_MODEL; k0 += 32) {
        __syncthreads();
        __builtin_amdgcn_global_load_lds(
            (const __attribute__((address_space(1))) void*)(gA0 + k0),
            (__attribute__((address_space(3))) void*)lA0, 16, 0, 0);
        __builtin_amdgcn_global_load_lds(
            (const __attribute__((address_space(1))) void*)(gA1 + k0),
            (__attribute__((address_space(3))) void*)lA1, 16, 0, 0);
        __builtin_amdgcn_global_load_lds(
            (const __attribute__((address_space(1))) void*)(gB0 + k0),
            (__attribute__((address_space(3))) void*)lB0, 16, 0, 0);
        __builtin_amdgcn_global_load_lds(
            (const __attribute__((address_space(1))) void*)(gB1 + k0),
            (__attribute__((address_space(3))) void*)lB1, 16, 0, 0);
        __syncthreads();

        short8 af[4], bf[4];
#pragma unroll
        for (int mt = 0; mt < 4; mt++) af[mt] = *(const short8*)(ap + mt * 512);
#pragma unroll
        for (int nt = 0; nt < 4; nt++) bf[nt] = *(const short8*)(bp + nt * 512);
#pragma unroll
        for (int mt = 0; mt < 4; mt++)
#pragma unroll
            for (int nt = 0; nt < 4; nt++)
                acc[mt][nt] = __builtin_amdgcn_mfma_f32_16x16x32_bf16(
                    af[mt], bf[nt], acc[mt][nt], 0, 0, 0);
    }

    const int col_loc = wn * 64 + (lane & 15);
    const int row_base = m0 + wm * 64 + (lane >> 4) * 4;
    float bv[4];
#pragma unroll
    for (int nt = 0; nt < 4; nt++) bv[nt] = bias[n0 + col_loc + nt * 16];
#pragma unroll
    for (int mt = 0; mt < 4; mt++) {
#pragma unroll
        for (int r = 0; r < 4; r++) {
            const int mm = row_base + mt * 16 + r;
            if (QKV_STORE) {
                const int bb = mm / rows_per_b;
                const int s = mm - bb * rows_per_b + C_s_off;
                ushort* dst = Cq + (((size_t)bb * NHEADS + blockIdx.y) * S_TOT + s) * DHEAD;
#pragma unroll
                for (int nt = 0; nt < 4; nt++)
                    dst[col_loc + nt * 16] = f2bf(acc[mt][nt][r] + bv[nt]);
            } else {
                float* dst = Cf + (size_t)mm * D_MODEL + n0;
#pragma unroll
                for (int nt = 0; nt < 4; nt++)
                    dst[col_loc + nt * 16] = acc[mt][nt][r] + bv[nt];
            }
        }
    }
}

// ---------------------------------------------------------------------------
// RMSNorm + RoPE in place on bf16 q/k ([B][H][S][DH]).  Wave per row.
// q path additionally folds in ATT_SCALE (so attn skips the per-score mult).
// ---------------------------------------------------------------------------
__global__ __launch_bounds__(256) void rmsrope_kernel(
    ushort* __restrict__ qbuf, ushort* __restrict__ kbuf,
    const float* __restrict__ gq, const float* __restrict__ gk,
    const float* __restrict__ gqa, const float* __restrict__ gka,
    const float* __restrict__ icos, const float* __restrict__ isin,
    const float* __restrict__ tcos, const float* __restrict__ tsin)
{
    const int t = threadIdx.x & 63;
    const int row = blockIdx.x * 4 + (threadIdx.x >> 6);
    const int s = row % S_TOT;
    const bool is_img = s < S_IMGC;
    ushort* __restrict__ buf = blockIdx.y ? kbuf : qbuf;
    const float* __restrict__ g =
        blockIdx.y ? (is_img ? gk : gka) : (is_img ? gq : gqa);
    const int pos = is_img ? s : s - S_IMGC;
    const float* __restrict__ ct = (is_img ? icos : tcos) + pos * 64;
    const float* __restrict__ st = (is_img ? isin : tsin) + pos * 64;
    const float qs = blockIdx.y ? 1.0f : ATT_SCALE;

    ushort* p = buf + (size_t)row * DHEAD + t * 2;
    uint u = *(uint*)p;
    const float x0 = __uint_as_float(u << 16);
    const float x1 = __uint_as_float(u & 0xffff0000u);
    float ss = x0 * x0 + x1 * x1;
#pragma unroll
    for (int off = 1; off < 64; off <<= 1) ss += __shfl_xor(ss, off, 64);
    const float r = rsqrtf(ss * (1.0f / DHEAD) + 1e-5f);
    const float y0 = x0 * r * g[t * 2];
    const float y1 = x1 * r * g[t * 2 + 1];
    const float c = ct[t], sn = st[t];
    const float o0 = (y0 * c - y1 * sn) * qs;
    const float o1 = (y0 * sn + y1 * c) * qs;
    *(uint*)p = (uint)f2bf(o0) | ((uint)f2bf(o1) << 16);
}

// ---------------------------------------------------------------------------
// MFMA flash attention, m214-style swapped QK^T (32x32x16 bf16).
// 256 threads = 4 waves; block = 128 q-rows; wave owns 32 q (one 32x32 tile).
// K-tile = 64 keys.  Round-6 change: T3/T4 counted-prefetch schedule.
//   __syncthreads() compiles to s_waitcnt vmcnt(0)+s_barrier (m97), which
//   drained the just-issued next-tile loads every iteration -> exposed
//   L2/HBM latency.  Now: raw s_barrier + explicit lgkmcnt(0) only;
//   loads for tile kt+2 are issued before the 2nd barrier and REMAIN IN
//   FLIGHT through it, landing under tile kt+1's whole compute phase.
//   The vmcnt wait before the LDS write is the compiler's register-dep
//   (counted), placed after a full compute phase of cover.
// Invariant entering iter kt: LDS = tile kt, loads(kt+1) in flight.
// ---------------------------------------------------------------------------
__global__ __launch_bounds__(256) void attn_kernel(
    const ushort* __restrict__ qb, const ushort* __restrict__ kb,
    const ushort* __restrict__ vtb, ushort* __restrict__ ob,
    const int* __restrict__ maskp)
{
    __shared__ __align__(16) ushort Ks[64 * 128];   // [key][dh], swizzled 256B rows
    __shared__ __align__(16) ushort Vts[128 * 64];  // [dh][key], swizzled 128B rows

    const int b = blockIdx.z, h = blockIdx.y;
    const int q0 = blockIdx.x * 128;
    const int tid = threadIdx.x;
    const int w = tid >> 6, lane = tid & 63;
    const int l5 = lane & 31, hi = lane >> 5;
    const size_t hb  = ((size_t)b * NHEADS + h) * S_TOT * DHEAD;
    const size_t hbt = ((size_t)b * NHEADS + h) * DHEAD * S_TOT;
    const ushort* kp  = kb + hb;
    const ushort* vtp = vtb + hbt;
    char* Kb = (char*)Ks;
    char* Vb = (char*)Vts;
    const int NT = S_TOT / 64;  // 36

    // Q fragments (regs): B-operand, n = l5 (q row), k = hi*8+j per 16-dh step
    short8 qf[8];
#pragma unroll
    for (int ks = 0; ks < 8; ks++)
        qf[ks] = *(const short8*)(qb + hb +
            (size_t)(q0 + w * 32 + l5) * DHEAD + ks * 16 + hi * 8);

    f32x16 o_acc[4];
#pragma unroll
    for (int nt = 0; nt < 4; nt++) o_acc[nt] = (f32x16)0.f;
    float mrow = -1e30f, lrow = 0.f;

    // ---- prologue: load tile 0, write it, issue loads for tile 1
    uint4 kpre[4], vpre[4];
#pragma unroll
    for (int i = 0; i < 4; i++) {
        const int c = tid + 256 * i;
        kpre[i] = *(const uint4*)(kp + (size_t)(c >> 4) * DHEAD + (c & 15) * 8);
        vpre[i] = *(const uint4*)(vtp + (size_t)(c >> 3) * S_TOT + (c & 7) * 8);
    }
#pragma unroll
    for (int i = 0; i < 4; i++) {
        const int c = tid + 256 * i;
        const int krow = c >> 4, kslot = c & 15;
        *(uint4*)(Kb + krow * 256 + ((kslot * 16) ^ ((krow & 15) << 4))) = kpre[i];
        const int vrow = c >> 3, vslot = c & 7;
        *(uint4*)(Vb + vrow * 128 + ((vslot * 16) ^ ((vrow & 7) << 4))) = vpre[i];
    }
#pragma unroll
    for (int i = 0; i < 4; i++) {
        const int c = tid + 256 * i;
        kpre[i] = *(const uint4*)(kp + (size_t)(64 + (c >> 4)) * DHEAD + (c & 15) * 8);
        vpre[i] = *(const uint4*)(vtp + (size_t)(c >> 3) * S_TOT + 64 + (c & 7) * 8);
    }
    asm volatile("s_waitcnt lgkmcnt(0)" ::: "memory");
    __builtin_amdgcn_sched_barrier(0);
    __builtin_amdgcn_s_barrier();   // tile 0 visible; tile-1 loads in flight

    for (int kt = 0; kt < NT; kt++) {
        const int k0 = kt * 64;

        // ---- S^T = K Q^T : two 32-key m-tiles, k over 128 dh
        f32x16 sa[2];
        sa[0] = (f32x16)0.f; sa[1] = (f32x16)0.f;
        __builtin_amdgcn_s_setprio(1);
#pragma unroll
        for (int ks = 0; ks < 8; ks++) {
#pragma unroll
            for (int mt = 0; mt < 2; mt++) {
                const int row = mt * 32 + l5;
                const short8 kfr = *(const short8*)(Kb + row * 256 +
                    ((ks * 32 + hi * 16) ^ ((row & 15) << 4)));
                sa[mt] = __builtin_amdgcn_mfma_f32_32x32x16_bf16(
                    kfr, qf[ks], sa[mt], 0, 0, 0);
            }
        }
        __builtin_amdgcn_s_setprio(0);

        // ---- mask (txt keys only; key = k0 + mt*32 + crow(r,hi))
        if (k0 >= S_IMGC) {
            const int kbase = b * S_TXTC + (k0 - S_IMGC) + 4 * hi;
#pragma unroll
            for (int mt = 0; mt < 2; mt++)
#pragma unroll
                for (int r = 0; r < 16; r++)
                    if (maskp[kbase + mt * 32 + (r & 3) + 8 * (r >> 2)] == 0)
                        sa[mt][r] = -1e9f;
        }

        // ---- online softmax: lane owns q = l5; lane+partner cover 64 keys
        float mx = sa[0][0];
#pragma unroll
        for (int r = 1; r < 16; r++) mx = fmaxf(mx, sa[0][r]);
#pragma unroll
        for (int r = 0; r < 16; r++) mx = fmaxf(mx, sa[1][r]);
        mx = fmaxf(mx, __shfl_xor(mx, 32, 64));

        if (!__all(mx <= mrow + 8.f)) {   // defer-max: rescale only on growth
            const float mn = fmaxf(mrow, mx);
            const float al = __expf(mrow - mn);
            mrow = mn;
            lrow *= al;
#pragma unroll
            for (int r = 0; r < 16; r++) {
                const float alr = __shfl(al, (r & 3) + 8 * (r >> 2) + 4 * hi, 64);
#pragma unroll
                for (int nt = 0; nt < 4; nt++) o_acc[nt][r] *= alr;
            }
        }
        float ps = 0.f;
#pragma unroll
        for (int mt = 0; mt < 2; mt++)
#pragma unroll
            for (int r = 0; r < 16; r++) {
                const float p = __expf(sa[mt][r] - mrow);
                sa[mt][r] = p;
                ps += p;
            }
        ps += __shfl_xor(ps, 32, 64);
        lrow += ps;

        // ---- P -> bf16 PV A-frags (in-register, cvt_pk + permlane32_swap)
        //      swap(LOWpair, HIpair): LOWpair.hi <-> HIpair.lo ->
        //      LOWpair_new = j01, HIpair_new = j45.
        short8 av[4];
#pragma unroll
        for (int ks = 0; ks < 4; ks++) {
            const int mt = ks >> 1, off = (ks & 1) * 8;
            uint B1 = pk_bf16(sa[mt][off + 0], sa[mt][off + 1]);
            uint A1 = pk_bf16(sa[mt][off + 4], sa[mt][off + 5]);
            uint B2 = pk_bf16(sa[mt][off + 2], sa[mt][off + 3]);
            uint A2 = pk_bf16(sa[mt][off + 6], sa[mt][off + 7]);
            asm volatile("v_permlane32_swap_b32 %0, %1" : "+v"(B1), "+v"(A1));
            asm volatile("v_permlane32_swap_b32 %0, %1" : "+v"(B2), "+v"(A2));
            union { uint4v u; short8 s; } cv;
            cv.u[0] = B1;  // j0,j1
            cv.u[1] = B2;  // j2,j3
            cv.u[2] = A1;  // j4,j5
            cv.u[3] = A2;  // j6,j7
            av[ks] = cv.s;
        }

        // ---- O += P V  (B = Vt rows, conflict-free swizzled b128)
        __builtin_amdgcn_s_setprio(1);
#pragma unroll
        for (int ks = 0; ks < 4; ks++) {
#pragma unroll
            for (int nt = 0; nt < 4; nt++) {
                const int row = nt * 32 + l5;
                const short8 vf = *(const short8*)(Vb + row * 128 +
                    ((ks * 32 + hi * 16) ^ ((row & 7) << 4)));
                o_acc[nt] = __builtin_amdgcn_mfma_f32_32x32x16_bf16(
                    av[ks], vf, o_acc[nt], 0, 0, 0);
            }
        }
        __builtin_amdgcn_s_setprio(0);

        // ---- staging for tile kt+1 (raw barriers; loads kt+2 span them)
        if (kt + 1 < NT) {
            asm volatile("s_waitcnt lgkmcnt(0)" ::: "memory");
            __builtin_amdgcn_sched_barrier(0);
            __builtin_amdgcn_s_barrier();   // all waves done reading tile kt
#pragma unroll
            for (int i = 0; i < 4; i++) {   // write kt+1 (vmcnt via reg-dep)
                const int c = tid + 256 * i;
                const int krow = c >> 4, kslot = c & 15;
                *(uint4*)(Kb + krow * 256 + ((kslot * 16) ^ ((krow & 15) << 4))) = kpre[i];
                const int vrow = c >> 3, vslot = c & 7;
                *(uint4*)(Vb + vrow * 128 + ((vslot * 16) ^ ((vrow & 7) << 4))) = vpre[i];
            }
            if (kt + 2 < NT) {              // issue loads kt+2, left in flight
                const int k0n = (kt + 2) * 64;
#pragma unroll
                for (int i = 0; i < 4; i++) {
                    const int c = tid + 256 * i;
                    kpre[i] = *(const uint4*)(kp + (size_t)(k0n + (c >> 4)) * DHEAD + (c & 15) * 8);
                    vpre[i] = *(const uint4*)(vtp + (size_t)(c >> 3) * S_TOT + k0n + (c & 7) * 8);
                }
            }
            asm volatile("s_waitcnt lgkmcnt(0)" ::: "memory");
            __builtin_amdgcn_sched_barrier(0);
            __builtin_amdgcn_s_barrier();   // kt+1 visible; kt+2 loads in flight
        }
    }

    // ---- epilogue: normalize, write bf16 O as [B][S][H*DH]
    const float linv = 1.0f / lrow;
#pragma unroll
    for (int r = 0; r < 16; r++) {
        const int crow = (r & 3) + 8 * (r >> 2) + 4 * hi;
        const float lr = __shfl(linv, crow, 64);
        const int s = q0 + w * 32 + crow;
        ushort* dst = ob + ((size_t)b * S_TOT + s) * D_MODEL + h * DHEAD + l5;
#pragma unroll
        for (int nt = 0; nt < 4; nt++)
            dst[nt * 32] = f2bf(o_acc[nt][r] * lr);
    }
}

// ---------------------------------------------------------------------------
extern "C" void kernel_launch(void* const* d_in, const int* in_sizes, int n_in,
                              void* d_out, int out_size, void* d_ws, size_t ws_size,
                              hipStream_t stream)
{
    const float* hidden = (const float*)d_in[0];
    const float* enc    = (const float*)d_in[1];
    const int* encmask  = (const int*)d_in[2];
    const float* icos = (const float*)d_in[4];
    const float* isin = (const float*)d_in[5];
    const float* tcos = (const float*)d_in[6];
    const float* tsin = (const float*)d_in[7];
    const float* wq  = (const float*)d_in[8];  const float* bq  = (const float*)d_in[9];
    const float* wk  = (const float*)d_in[10]; const float* bk  = (const float*)d_in[11];
    const float* wv  = (const float*)d_in[12]; const float* bv  = (const float*)d_in[13];
    const float* wqa = (const float*)d_in[14]; const float* bqa = (const float*)d_in[15];
    const float* wka = (const float*)d_in[16]; const float* bka = (const float*)d_in[17];
    const float* wva = (const float*)d_in[18]; const float* bva = (const float*)d_in[19];
    const float* wo  = (const float*)d_in[20]; const float* bo  = (const float*)d_in[21];
    const float* woa = (const float*)d_in[22]; const float* boa = (const float*)d_in[23];
    const float* gq  = (const float*)d_in[24]; const float* gk  = (const float*)d_in[25];
    const float* gqa = (const float*)d_in[26]; const float* gka = (const float*)d_in[27];
    float* out = (float*)d_out;

    const size_t W_ELE = (size_t)D_MODEL * D_MODEL;
    const size_t NQKV  = (size_t)BATCH * NHEADS * S_TOT * DHEAD;
    char* p = (char*)d_ws;
    ushort* wT0 = (ushort*)p; p += W_ELE * 2;
    ushort* wT1 = (ushort*)p; p += W_ELE * 2;
    ushort* wT2 = (ushort*)p; p += W_ELE * 2;
    ushort* ximg = (ushort*)p; p += (size_t)BATCH * S_IMGC * D_MODEL * 2;
    ushort* xtxt = (ushort*)p; p += (size_t)BATCH * S_TXTC * D_MODEL * 2;
    ushort* qbuf = (ushort*)p; p += NQKV * 2;
    ushort* kbuf = (ushort*)p; p += NQKV * 2;
    ushort* vbuf = (ushort*)p; p += NQKV * 2;
    ushort* vtbuf = (ushort*)p; p += NQKV * 2;
    ushort* obuf = (ushort*)p; p += (size_t)BATCH * S_TOT * D_MODEL * 2;
    if ((size_t)(p - (char*)d_ws) > ws_size) return;  // 226.5 MB needed

    const dim3 blk(256);

    cvt_kernel<<<dim3((BATCH * S_IMGC * D_MODEL / 4 + 255) / 256), blk, 0, stream>>>(
        hidden, ximg, BATCH * S_IMGC * D_MODEL / 4);
    cvt_kernel<<<dim3((BATCH * S_TXTC * D_MODEL / 4 + 255) / 256), blk, 0, stream>>>(
        enc, xtxt, BATCH * S_TXTC * D_MODEL / 4);

    transpose_w<<<dim3(48, 48, 3), blk, 0, stream>>>(wq, wk, wv, wT0, wT1, wT2);
    gemm_bf16<true><<<dim3(32, 24, 3), blk, 0, stream>>>(
        ximg, (size_t)S_IMGC * D_MODEL, 0, S_IMGC,
        wT0, wT1, wT2, bq, bk, bv, qbuf, kbuf, vbuf, nullptr, 0);
    transpose_w<<<dim3(48, 48, 3), blk, 0, stream>>>(wqa, wka, wva, wT0, wT1, wT2);
    gemm_bf16<true><<<dim3(4, 24, 3), blk, 0, stream>>>(
        xtxt, (size_t)S_TXTC * D_MODEL, 0, S_TXTC,
        wT0, wT1, wT2, bqa, bka, bva, qbuf, kbuf, vbuf, nullptr, S_IMGC);

    rmsrope_kernel<<<dim3(BATCH * NHEADS * S_TOT / 4, 2), blk, 0, stream>>>(
        qbuf, kbuf, gq, gk, gqa, gka, icos, isin, tcos, tsin);

    transpose_v<<<dim3(S_TOT / 64, DHEAD / 64, BATCH * NHEADS), blk, 0, stream>>>(
        vbuf, vtbuf);

    attn_kernel<<<dim3(S_TOT / 128, NHEADS, BATCH), blk, 0, stream>>>(
        qbuf, kbuf, vtbuf, obuf, encmask);

    transpose_w<<<dim3(48, 48, 1), blk, 0, stream>>>(wo, wo, wo, wT0, wT0, wT0);
    gemm_bf16<false><<<dim3(32, 24, 1), blk, 0, stream>>>(
        obuf, (size_t)S_TOT * D_MODEL, 0, S_IMGC,
        wT0, wT0, wT0, bo, bo, bo, nullptr, nullptr, nullptr, out, 0);
    transpose_w<<<dim3(48, 48, 1), blk, 0, stream>>>(woa, woa, woa, wT0, wT0, wT0);
    gemm_bf16<false><<<dim3(4, 24, 1), blk, 0, stream>>>(
        obuf, (size_t)S_TOT * D_MODEL, S_IMGC, S_TXTC,
        wT0, wT0, wT0, boa, boa, boa, nullptr, nullptr, nullptr,
        out + (size_t)BATCH * S_IMGC * D_MODEL, 0);
}

// Round 4
// 1181.805 us; speedup vs baseline: 1.1861x; 1.1861x over previous
//
#include <hip/hip_runtime.h>
#include <cstdint>
#include <cstddef>

// ---------------------------------------------------------------------------
// QwenDoubleStreamAttention — round 7: 8-wave/256-q attn blocks (m214 geometry)
// + bijective chunked XCD swizzle for K/V L2 locality.
//   B=2, S_img=2048, S_txt=256 (S=2304), D=3072, H=24, DH=128.
// Pipeline:
//   cvt_kernel       : hidden/enc fp32 -> bf16
//   transpose_w      : W fp32 [k][n] -> bf16 [n][k]
//   gemm_bf16<true>  : MFMA qkv proj -> bf16 [B][H][S][DH]
//   rmsrope_kernel   : RMSNorm + RoPE on q,k in place (q pre-scaled by DH^-0.5)
//   transpose_v      : V [B][H][S][DH] -> Vt [B][H][DH][S]
//   attn_kernel      : 512 thr / 8 waves / 256 q-rows per block; 32x32x16
//                      swapped-QK^T flash attention, in-register softmax
//                      (cvt_pk + permlane32_swap), XOR-swizzled K/Vt LDS
//                      (32 KB shared by 8 waves), defer-max, raw-barrier
//                      counted-prefetch staging; 1-D grid 432 with
//                      (bid&7)*54+bid/8 payload remap -> each XCD owns
//                      contiguous (b,h) groups (K/V L2-resident).
//   gemm_bf16<false> : MFMA out-proj -> d_out fp32
// Workspace: 226,492,416 B (round-1 budget, proven available).
// ---------------------------------------------------------------------------

#define D_MODEL 3072
#define NHEADS 24
#define DHEAD 128
#define S_IMGC 2048
#define S_TXTC 256
#define S_TOT 2304
#define BATCH 2
#define ATT_SCALE 0.08838834764831845f  // 128^-0.5

typedef __attribute__((ext_vector_type(8))) short short8;   // 8 bf16 = 4 VGPR
typedef __attribute__((ext_vector_type(4))) float f32x4;
typedef __attribute__((ext_vector_type(16))) float f32x16;
typedef __attribute__((ext_vector_type(4))) unsigned int uint4v;

__device__ __forceinline__ ushort f2bf(float f) {  // fp32 -> bf16 RNE
    uint u = __float_as_uint(f);
    return (ushort)((u + 0x7fffu + ((u >> 16) & 1u)) >> 16);
}

__device__ __forceinline__ uint pk_bf16(float lo, float hi) {
    uint r;
    asm("v_cvt_pk_bf16_f32 %0, %1, %2" : "=v"(r) : "v"(lo), "v"(hi));
    return r;
}

// ---------------------------------------------------------------------------
__global__ __launch_bounds__(256) void cvt_kernel(
    const float* __restrict__ src, ushort* __restrict__ dst, int n4)
{
    int i = blockIdx.x * 256 + threadIdx.x;
    if (i >= n4) return;
    float4 v = ((const float4*)src)[i];
    ushort4 o;
    o.x = f2bf(v.x); o.y = f2bf(v.y); o.z = f2bf(v.z); o.w = f2bf(v.w);
    ((ushort4*)dst)[i] = o;
}

// ---------------------------------------------------------------------------
// W fp32 [k][n] -> bf16 [n][k].  64x64 LDS tile; grid.z picks weight.
// ---------------------------------------------------------------------------
__global__ __launch_bounds__(256) void transpose_w(
    const float* __restrict__ W0, const float* __restrict__ W1,
    const float* __restrict__ W2,
    ushort* __restrict__ T0, ushort* __restrict__ T1, ushort* __restrict__ T2)
{
    __shared__ float tile[64][68];
    const int z = blockIdx.z;
    const float* __restrict__ W = (z == 0) ? W0 : (z == 1) ? W1 : W2;
    ushort* __restrict__ T      = (z == 0) ? T0 : (z == 1) ? T1 : T2;
    const int tid = threadIdx.x;
    const int k0 = blockIdx.x * 64, n0 = blockIdx.y * 64;
    const int r = tid >> 4, c4 = (tid & 15) * 4;
#pragma unroll
    for (int i = 0; i < 4; i++) {
        float4 v = *(const float4*)(W + (size_t)(k0 + r + 16 * i) * D_MODEL + n0 + c4);
        *(float4*)&tile[r + 16 * i][c4] = v;
    }
    __syncthreads();
#pragma unroll
    for (int i = 0; i < 4; i++) {
        const int nn = n0 + r + 16 * i;
        ushort4 o;
        o.x = f2bf(tile[c4 + 0][r + 16 * i]);
        o.y = f2bf(tile[c4 + 1][r + 16 * i]);
        o.z = f2bf(tile[c4 + 2][r + 16 * i]);
        o.w = f2bf(tile[c4 + 3][r + 16 * i]);
        *(ushort4*)(T + (size_t)nn * D_MODEL + k0 + c4) = o;
    }
}

// ---------------------------------------------------------------------------
// V bf16 [B][H][S][DH] -> Vt bf16 [B][H][DH][S].  64x64 tiles.
// ---------------------------------------------------------------------------
__global__ __launch_bounds__(256) void transpose_v(
    const ushort* __restrict__ v, ushort* __restrict__ vt)
{
    __shared__ ushort t[64][72];
    const int bh = blockIdx.z;
    const int s0 = blockIdx.x * 64, d0 = blockIdx.y * 64;
    const size_t base  = (size_t)bh * S_TOT * DHEAD;
    const size_t baset = (size_t)bh * DHEAD * S_TOT;
    const int tid = threadIdx.x;
#pragma unroll
    for (int i = 0; i < 2; i++) {
        int id = tid + 256 * i;
        int r = id >> 3, c = (id & 7) * 8;
        *(uint4*)&t[r][c] = *(const uint4*)(v + base + (size_t)(s0 + r) * DHEAD + d0 + c);
    }
    __syncthreads();
#pragma unroll
    for (int i = 0; i < 2; i++) {
        int id = tid + 256 * i;
        int r = id >> 3, c = (id & 7) * 8;  // r = dh_loc, c = s chunk base
        ushort tmp[8];
#pragma unroll
        for (int j = 0; j < 8; j++) tmp[j] = t[c + j][r];
        *(uint4*)(vt + baset + (size_t)(d0 + r) * S_TOT + s0 + c) = *(uint4*)tmp;
    }
}

// ---------------------------------------------------------------------------
// MFMA GEMM (round-2 structure, unchanged).
// ---------------------------------------------------------------------------
template <bool QKV_STORE>
__global__ __launch_bounds__(256) void gemm_bf16(
    const ushort* __restrict__ A, size_t A_bstride, int As_off, int rows_per_b,
    const ushort* __restrict__ B0, const ushort* __restrict__ B1,
    const ushort* __restrict__ B2,
    const float* __restrict__ bi0, const float* __restrict__ bi1,
    const float* __restrict__ bi2,
    ushort* __restrict__ Q0, ushort* __restrict__ Q1, ushort* __restrict__ Q2,
    float* __restrict__ Cf, int C_s_off)
{
    __shared__ ushort As[128 * 32];
    __shared__ ushort Bs[128 * 32];

    const int z = blockIdx.z;
    const ushort* __restrict__ Wt  = (z == 0) ? B0 : (z == 1) ? B1 : B2;
    const float* __restrict__ bias = (z == 0) ? bi0 : (z == 1) ? bi1 : bi2;
    ushort* __restrict__ Cq        = (z == 0) ? Q0 : (z == 1) ? Q1 : Q2;

    const int tid = threadIdx.x;
    const int w = tid >> 6, lane = tid & 63;
    const int m0 = blockIdx.x * 128, n0 = blockIdx.y * 128;
    const int wm = w & 1, wn = w >> 1;

    const int ar0 = w * 32 + (lane >> 2);
    const int ar1 = ar0 + 16;
    const int acol = (lane & 3) * 8;
    const int ma0 = m0 + ar0, ma1 = m0 + ar1;
    const ushort* gA0 = A + (size_t)(ma0 / rows_per_b) * A_bstride +
                        (size_t)(ma0 % rows_per_b + As_off) * D_MODEL + acol;
    const ushort* gA1 = A + (size_t)(ma1 / rows_per_b) * A_bstride +
                        (size_t)(ma1 % rows_per_b + As_off) * D_MODEL + acol;
    const ushort* gB0 = Wt + (size_t)(n0 + ar0) * D_MODEL + acol;
    const ushort* gB1 = Wt + (size_t)(n0 + ar1) * D_MODEL + acol;
    ushort* lA0 = As + (w * 32) * 32;
    ushort* lA1 = As + (w * 32 + 16) * 32;
    ushort* lB0 = Bs + (w * 32) * 32;
    ushort* lB1 = Bs + (w * 32 + 16) * 32;

    f32x4 acc[4][4];
#pragma unroll
    for (int i = 0; i < 4; i++)
#pragma unroll
        for (int j = 0; j < 4; j++) acc[i][j] = (f32x4)0.f;

    const ushort* ap = As + (wm * 64 + (lane & 15)) * 32 + (lane >> 4) * 8;
    const ushort* bp = Bs + (wn * 64 + (lane & 15)) * 32 + (lane >> 4) * 8;

    for (int k0 = 0; k0 < D_MODEL; k0 += 32) {
        __syncthreads();
        __builtin_amdgcn_global_load_lds(
            (const __attribute__((address_space(1))) void*)(gA0 + k0),
            (__attribute__((address_space(3))) void*)lA0, 16, 0, 0);
        __builtin_amdgcn_global_load_lds(
            (const __attribute__((address_space(1))) void*)(gA1 + k0),
            (__attribute__((address_space(3))) void*)lA1, 16, 0, 0);
        __builtin_amdgcn_global_load_lds(
            (const __attribute__((address_space(1))) void*)(gB0 + k0),
            (__attribute__((address_space(3))) void*)lB0, 16, 0, 0);
        __builtin_amdgcn_global_load_lds(
            (const __attribute__((address_space(1))) void*)(gB1 + k0),
            (__attribute__((address_space(3))) void*)lB1, 16, 0, 0);
        __syncthreads();

        short8 af[4], bf[4];
#pragma unroll
        for (int mt = 0; mt < 4; mt++) af[mt] = *(const short8*)(ap + mt * 512);
#pragma unroll
        for (int nt = 0; nt < 4; nt++) bf[nt] = *(const short8*)(bp + nt * 512);
#pragma unroll
        for (int mt = 0; mt < 4; mt++)
#pragma unroll
            for (int nt = 0; nt < 4; nt++)
                acc[mt][nt] = __builtin_amdgcn_mfma_f32_16x16x32_bf16(
                    af[mt], bf[nt], acc[mt][nt], 0, 0, 0);
    }

    const int col_loc = wn * 64 + (lane & 15);
    const int row_base = m0 + wm * 64 + (lane >> 4) * 4;
    float bv[4];
#pragma unroll
    for (int nt = 0; nt < 4; nt++) bv[nt] = bias[n0 + col_loc + nt * 16];
#pragma unroll
    for (int mt = 0; mt < 4; mt++) {
#pragma unroll
        for (int r = 0; r < 4; r++) {
            const int mm = row_base + mt * 16 + r;
            if (QKV_STORE) {
                const int bb = mm / rows_per_b;
                const int s = mm - bb * rows_per_b + C_s_off;
                ushort* dst = Cq + (((size_t)bb * NHEADS + blockIdx.y) * S_TOT + s) * DHEAD;
#pragma unroll
                for (int nt = 0; nt < 4; nt++)
                    dst[col_loc + nt * 16] = f2bf(acc[mt][nt][r] + bv[nt]);
            } else {
                float* dst = Cf + (size_t)mm * D_MODEL + n0;
#pragma unroll
                for (int nt = 0; nt < 4; nt++)
                    dst[col_loc + nt * 16] = acc[mt][nt][r] + bv[nt];
            }
        }
    }
}

// ---------------------------------------------------------------------------
// RMSNorm + RoPE in place on bf16 q/k ([B][H][S][DH]).  Wave per row.
// q path additionally folds in ATT_SCALE (so attn skips the per-score mult).
// ---------------------------------------------------------------------------
__global__ __launch_bounds__(256) void rmsrope_kernel(
    ushort* __restrict__ qbuf, ushort* __restrict__ kbuf,
    const float* __restrict__ gq, const float* __restrict__ gk,
    const float* __restrict__ gqa, const float* __restrict__ gka,
    const float* __restrict__ icos, const float* __restrict__ isin,
    const float* __restrict__ tcos, const float* __restrict__ tsin)
{
    const int t = threadIdx.x & 63;
    const int row = blockIdx.x * 4 + (threadIdx.x >> 6);
    const int s = row % S_TOT;
    const bool is_img = s < S_IMGC;
    ushort* __restrict__ buf = blockIdx.y ? kbuf : qbuf;
    const float* __restrict__ g =
        blockIdx.y ? (is_img ? gk : gka) : (is_img ? gq : gqa);
    const int pos = is_img ? s : s - S_IMGC;
    const float* __restrict__ ct = (is_img ? icos : tcos) + pos * 64;
    const float* __restrict__ st = (is_img ? isin : tsin) + pos * 64;
    const float qs = blockIdx.y ? 1.0f : ATT_SCALE;

    ushort* p = buf + (size_t)row * DHEAD + t * 2;
    uint u = *(uint*)p;
    const float x0 = __uint_as_float(u << 16);
    const float x1 = __uint_as_float(u & 0xffff0000u);
    float ss = x0 * x0 + x1 * x1;
#pragma unroll
    for (int off = 1; off < 64; off <<= 1) ss += __shfl_xor(ss, off, 64);
    const float r = rsqrtf(ss * (1.0f / DHEAD) + 1e-5f);
    const float y0 = x0 * r * g[t * 2];
    const float y1 = x1 * r * g[t * 2 + 1];
    const float c = ct[t], sn = st[t];
    const float o0 = (y0 * c - y1 * sn) * qs;
    const float o1 = (y0 * sn + y1 * c) * qs;
    *(uint*)p = (uint)f2bf(o0) | ((uint)f2bf(o1) << 16);
}

// ---------------------------------------------------------------------------
// MFMA flash attention, m214 8-wave geometry: 512 threads = 8 waves, block
// owns 256 q-rows (wave w -> q = q0 + w*32 .. +31), K-tile = 64 keys.
// Same per-wave inner math as round 5/6 (verified passing):
//   swapped QK^T (mfma(K,Q)) -> lane-local P rows; in-register softmax;
//   P->PV frags via cvt_pk + permlane32_swap; XOR-swizzled K/Vt LDS;
//   defer-max; raw-barrier counted-prefetch staging (loads kt+2 in flight
//   across barriers; vmcnt covered by one full compute phase).
// Staging split over 512 threads: 2 x uint4 each for K and Vt.
// Grid: 1-D 432 blocks with bijective chunked XCD remap
//   pid = (bid&7)*54 + bid>>3  ->  each XCD gets 54 consecutive payloads
//   = 6 whole (b,h) groups -> K/V L2-resident per XCD (T1, m204 form).
// ---------------------------------------------------------------------------
__global__ __launch_bounds__(512) void attn_kernel(
    const ushort* __restrict__ qb, const ushort* __restrict__ kb,
    const ushort* __restrict__ vtb, ushort* __restrict__ ob,
    const int* __restrict__ maskp)
{
    __shared__ __align__(16) ushort Ks[64 * 128];   // [key][dh], swizzled 256B rows
    __shared__ __align__(16) ushort Vts[128 * 64];  // [dh][key], swizzled 128B rows

    // --- chunked XCD swizzle: 432 = 8 * 54; payload = (b,h,x) x-fastest
    const int bid = blockIdx.x;
    const int pid = (bid & 7) * 54 + (bid >> 3);
    const int x   = pid % 9;
    const int bh_ = pid / 9;          // 0..47
    const int h   = bh_ % 24;
    const int b   = bh_ / 24;
    const int q0  = x * 256;

    const int tid = threadIdx.x;
    const int w = tid >> 6, lane = tid & 63;
    const int l5 = lane & 31, hi = lane >> 5;
    const size_t hb  = ((size_t)b * NHEADS + h) * S_TOT * DHEAD;
    const size_t hbt = ((size_t)b * NHEADS + h) * DHEAD * S_TOT;
    const ushort* kp  = kb + hb;
    const ushort* vtp = vtb + hbt;
    char* Kb = (char*)Ks;
    char* Vb = (char*)Vts;
    const int NT = S_TOT / 64;  // 36

    // Q fragments (regs): B-operand, n = l5 (q row), k = hi*8+j per 16-dh step
    short8 qf[8];
#pragma unroll
    for (int ks = 0; ks < 8; ks++)
        qf[ks] = *(const short8*)(qb + hb +
            (size_t)(q0 + w * 32 + l5) * DHEAD + ks * 16 + hi * 8);

    f32x16 o_acc[4];
#pragma unroll
    for (int nt = 0; nt < 4; nt++) o_acc[nt] = (f32x16)0.f;
    float mrow = -1e30f, lrow = 0.f;

    // ---- prologue: load tile 0, write it, issue loads for tile 1
    uint4 kpre[2], vpre[2];
#pragma unroll
    for (int i = 0; i < 2; i++) {
        const int c = tid + 512 * i;
        kpre[i] = *(const uint4*)(kp + (size_t)(c >> 4) * DHEAD + (c & 15) * 8);
        vpre[i] = *(const uint4*)(vtp + (size_t)(c >> 3) * S_TOT + (c & 7) * 8);
    }
#pragma unroll
    for (int i = 0; i < 2; i++) {
        const int c = tid + 512 * i;
        const int krow = c >> 4, kslot = c & 15;
        *(uint4*)(Kb + krow * 256 + ((kslot * 16) ^ ((krow & 15) << 4))) = kpre[i];
        const int vrow = c >> 3, vslot = c & 7;
        *(uint4*)(Vb + vrow * 128 + ((vslot * 16) ^ ((vrow & 7) << 4))) = vpre[i];
    }
#pragma unroll
    for (int i = 0; i < 2; i++) {
        const int c = tid + 512 * i;
        kpre[i] = *(const uint4*)(kp + (size_t)(64 + (c >> 4)) * DHEAD + (c & 15) * 8);
        vpre[i] = *(const uint4*)(vtp + (size_t)(c >> 3) * S_TOT + 64 + (c & 7) * 8);
    }
    asm volatile("s_waitcnt lgkmcnt(0)" ::: "memory");
    __builtin_amdgcn_sched_barrier(0);
    __builtin_amdgcn_s_barrier();   // tile 0 visible; tile-1 loads in flight

    for (int kt = 0; kt < NT; kt++) {
        const int k0 = kt * 64;

        // ---- S^T = K Q^T : two 32-key m-tiles, k over 128 dh
        f32x16 sa[2];
        sa[0] = (f32x16)0.f; sa[1] = (f32x16)0.f;
        __builtin_amdgcn_s_setprio(1);
#pragma unroll
        for (int ks = 0; ks < 8; ks++) {
#pragma unroll
            for (int mt = 0; mt < 2; mt++) {
                const int row = mt * 32 + l5;
                const short8 kfr = *(const short8*)(Kb + row * 256 +
                    ((ks * 32 + hi * 16) ^ ((row & 15) << 4)));
                sa[mt] = __builtin_amdgcn_mfma_f32_32x32x16_bf16(
                    kfr, qf[ks], sa[mt], 0, 0, 0);
            }
        }
        __builtin_amdgcn_s_setprio(0);

        // ---- mask (txt keys only; key = k0 + mt*32 + crow(r,hi))
        if (k0 >= S_IMGC) {
            const int kbase = b * S_TXTC + (k0 - S_IMGC) + 4 * hi;
#pragma unroll
            for (int mt = 0; mt < 2; mt++)
#pragma unroll
                for (int r = 0; r < 16; r++)
                    if (maskp[kbase + mt * 32 + (r & 3) + 8 * (r >> 2)] == 0)
                        sa[mt][r] = -1e9f;
        }

        // ---- online softmax: lane owns q = l5; lane+partner cover 64 keys
        float mx = sa[0][0];
#pragma unroll
        for (int r = 1; r < 16; r++) mx = fmaxf(mx, sa[0][r]);
#pragma unroll
        for (int r = 0; r < 16; r++) mx = fmaxf(mx, sa[1][r]);
        mx = fmaxf(mx, __shfl_xor(mx, 32, 64));

        if (!__all(mx <= mrow + 8.f)) {   // defer-max: rescale only on growth
            const float mn = fmaxf(mrow, mx);
            const float al = __expf(mrow - mn);
            mrow = mn;
            lrow *= al;
#pragma unroll
            for (int r = 0; r < 16; r++) {
                const float alr = __shfl(al, (r & 3) + 8 * (r >> 2) + 4 * hi, 64);
#pragma unroll
                for (int nt = 0; nt < 4; nt++) o_acc[nt][r] *= alr;
            }
        }
        float ps = 0.f;
#pragma unroll
        for (int mt = 0; mt < 2; mt++)
#pragma unroll
            for (int r = 0; r < 16; r++) {
                const float p = __expf(sa[mt][r] - mrow);
                sa[mt][r] = p;
                ps += p;
            }
        ps += __shfl_xor(ps, 32, 64);
        lrow += ps;

        // ---- P -> bf16 PV A-frags (in-register, cvt_pk + permlane32_swap)
        //      swap(LOWpair, HIpair): LOWpair.hi <-> HIpair.lo ->
        //      LOWpair_new = j01, HIpair_new = j45.
        short8 av[4];
#pragma unroll
        for (int ks = 0; ks < 4; ks++) {
            const int mt = ks >> 1, off = (ks & 1) * 8;
            uint B1 = pk_bf16(sa[mt][off + 0], sa[mt][off + 1]);
            uint A1 = pk_bf16(sa[mt][off + 4], sa[mt][off + 5]);
            uint B2 = pk_bf16(sa[mt][off + 2], sa[mt][off + 3]);
            uint A2 = pk_bf16(sa[mt][off + 6], sa[mt][off + 7]);
            asm volatile("v_permlane32_swap_b32 %0, %1" : "+v"(B1), "+v"(A1));
            asm volatile("v_permlane32_swap_b32 %0, %1" : "+v"(B2), "+v"(A2));
            union { uint4v u; short8 s; } cv;
            cv.u[0] = B1;  // j0,j1
            cv.u[1] = B2;  // j2,j3
            cv.u[2] = A1;  // j4,j5
            cv.u[3] = A2;  // j6,j7
            av[ks] = cv.s;
        }

        // ---- O += P V  (B = Vt rows, conflict-free swizzled b128)
        __builtin_amdgcn_s_setprio(1);
#pragma unroll
        for (int ks = 0; ks < 4; ks++) {
#pragma unroll
            for (int nt = 0; nt < 4; nt++) {
                const int row = nt * 32 + l5;
                const short8 vf = *(const short8*)(Vb + row * 128 +
                    ((ks * 32 + hi * 16) ^ ((row & 7) << 4)));
                o_acc[nt] = __builtin_amdgcn_mfma_f32_32x32x16_bf16(
                    av[ks], vf, o_acc[nt], 0, 0, 0);
            }
        }
        __builtin_amdgcn_s_setprio(0);

        // ---- staging for tile kt+1 (raw barriers; loads kt+2 span them)
        if (kt + 1 < NT) {
            asm volatile("s_waitcnt lgkmcnt(0)" ::: "memory");
            __builtin_amdgcn_sched_barrier(0);
            __builtin_amdgcn_s_barrier();   // all waves done reading tile kt
#pragma unroll
            for (int i = 0; i < 2; i++) {   // write kt+1 (vmcnt via reg-dep)
                const int c = tid + 512 * i;
                const int krow = c >> 4, kslot = c & 15;
                *(uint4*)(Kb + krow * 256 + ((kslot * 16) ^ ((krow & 15) << 4))) = kpre[i];
                const int vrow = c >> 3, vslot = c & 7;
                *(uint4*)(Vb + vrow * 128 + ((vslot * 16) ^ ((vrow & 7) << 4))) = vpre[i];
            }
            if (kt + 2 < NT) {              // issue loads kt+2, left in flight
                const int k0n = (kt + 2) * 64;
#pragma unroll
                for (int i = 0; i < 2; i++) {
                    const int c = tid + 512 * i;
                    kpre[i] = *(const uint4*)(kp + (size_t)(k0n + (c >> 4)) * DHEAD + (c & 15) * 8);
                    vpre[i] = *(const uint4*)(vtp + (size_t)(c >> 3) * S_TOT + k0n + (c & 7) * 8);
                }
            }
            asm volatile("s_waitcnt lgkmcnt(0)" ::: "memory");
            __builtin_amdgcn_sched_barrier(0);
            __builtin_amdgcn_s_barrier();   // kt+1 visible; kt+2 loads in flight
        }
    }

    // ---- epilogue: normalize, write bf16 O as [B][S][H*DH]
    const float linv = 1.0f / lrow;
#pragma unroll
    for (int r = 0; r < 16; r++) {
        const int crow = (r & 3) + 8 * (r >> 2) + 4 * hi;
        const float lr = __shfl(linv, crow, 64);
        const int s = q0 + w * 32 + crow;
        ushort* dst = ob + ((size_t)b * S_TOT + s) * D_MODEL + h * DHEAD + l5;
#pragma unroll
        for (int nt = 0; nt < 4; nt++)
            dst[nt * 32] = f2bf(o_acc[nt][r] * lr);
    }
}

// ---------------------------------------------------------------------------
extern "C" void kernel_launch(void* const* d_in, const int* in_sizes, int n_in,
                              void* d_out, int out_size, void* d_ws, size_t ws_size,
                              hipStream_t stream)
{
    const float* hidden = (const float*)d_in[0];
    const float* enc    = (const float*)d_in[1];
    const int* encmask  = (const int*)d_in[2];
    const float* icos = (const float*)d_in[4];
    const float* isin = (const float*)d_in[5];
    const float* tcos = (const float*)d_in[6];
    const float* tsin = (const float*)d_in[7];
    const float* wq  = (const float*)d_in[8];  const float* bq  = (const float*)d_in[9];
    const float* wk  = (const float*)d_in[10]; const float* bk  = (const float*)d_in[11];
    const float* wv  = (const float*)d_in[12]; const float* bv  = (const float*)d_in[13];
    const float* wqa = (const float*)d_in[14]; const float* bqa = (const float*)d_in[15];
    const float* wka = (const float*)d_in[16]; const float* bka = (const float*)d_in[17];
    const float* wva = (const float*)d_in[18]; const float* bva = (const float*)d_in[19];
    const float* wo  = (const float*)d_in[20]; const float* bo  = (const float*)d_in[21];
    const float* woa = (const float*)d_in[22]; const float* boa = (const float*)d_in[23];
    const float* gq  = (const float*)d_in[24]; const float* gk  = (const float*)d_in[25];
    const float* gqa = (const float*)d_in[26]; const float* gka = (const float*)d_in[27];
    float* out = (float*)d_out;

    const size_t W_ELE = (size_t)D_MODEL * D_MODEL;
    const size_t NQKV  = (size_t)BATCH * NHEADS * S_TOT * DHEAD;
    char* p = (char*)d_ws;
    ushort* wT0 = (ushort*)p; p += W_ELE * 2;
    ushort* wT1 = (ushort*)p; p += W_ELE * 2;
    ushort* wT2 = (ushort*)p; p += W_ELE * 2;
    ushort* ximg = (ushort*)p; p += (size_t)BATCH * S_IMGC * D_MODEL * 2;
    ushort* xtxt = (ushort*)p; p += (size_t)BATCH * S_TXTC * D_MODEL * 2;
    ushort* qbuf = (ushort*)p; p += NQKV * 2;
    ushort* kbuf = (ushort*)p; p += NQKV * 2;
    ushort* vbuf = (ushort*)p; p += NQKV * 2;
    ushort* vtbuf = (ushort*)p; p += NQKV * 2;
    ushort* obuf = (ushort*)p; p += (size_t)BATCH * S_TOT * D_MODEL * 2;
    if ((size_t)(p - (char*)d_ws) > ws_size) return;  // 226.5 MB needed

    const dim3 blk(256);

    cvt_kernel<<<dim3((BATCH * S_IMGC * D_MODEL / 4 + 255) / 256), blk, 0, stream>>>(
        hidden, ximg, BATCH * S_IMGC * D_MODEL / 4);
    cvt_kernel<<<dim3((BATCH * S_TXTC * D_MODEL / 4 + 255) / 256), blk, 0, stream>>>(
        enc, xtxt, BATCH * S_TXTC * D_MODEL / 4);

    transpose_w<<<dim3(48, 48, 3), blk, 0, stream>>>(wq, wk, wv, wT0, wT1, wT2);
    gemm_bf16<true><<<dim3(32, 24, 3), blk, 0, stream>>>(
        ximg, (size_t)S_IMGC * D_MODEL, 0, S_IMGC,
        wT0, wT1, wT2, bq, bk, bv, qbuf, kbuf, vbuf, nullptr, 0);
    transpose_w<<<dim3(48, 48, 3), blk, 0, stream>>>(wqa, wka, wva, wT0, wT1, wT2);
    gemm_bf16<true><<<dim3(4, 24, 3), blk, 0, stream>>>(
        xtxt, (size_t)S_TXTC * D_MODEL, 0, S_TXTC,
        wT0, wT1, wT2, bqa, bka, bva, qbuf, kbuf, vbuf, nullptr, S_IMGC);

    rmsrope_kernel<<<dim3(BATCH * NHEADS * S_TOT / 4, 2), blk, 0, stream>>>(
        qbuf, kbuf, gq, gk, gqa, gka, icos, isin, tcos, tsin);

    transpose_v<<<dim3(S_TOT / 64, DHEAD / 64, BATCH * NHEADS), blk, 0, stream>>>(
        vbuf, vtbuf);

    attn_kernel<<<dim3(432), dim3(512), 0, stream>>>(
        qbuf, kbuf, vtbuf, obuf, encmask);

    transpose_w<<<dim3(48, 48, 1), blk, 0, stream>>>(wo, wo, wo, wT0, wT0, wT0);
    gemm_bf16<false><<<dim3(32, 24, 1), blk, 0, stream>>>(
        obuf, (size_t)S_TOT * D_MODEL, 0, S_IMGC,
        wT0, wT0, wT0, bo, bo, bo, nullptr, nullptr, nullptr, out, 0);
    transpose_w<<<dim3(48, 48, 1), blk, 0, stream>>>(woa, woa, woa, wT0, wT0, wT0);
    gemm_bf16<false><<<dim3(4, 24, 1), blk, 0, stream>>>(
        obuf, (size_t)S_TOT * D_MODEL, S_IMGC, S_TXTC,
        wT0, wT0, wT0, boa, boa, boa, nullptr, nullptr, nullptr,
        out + (size_t)BATCH * S_IMGC * D_MODEL, 0);
}

// Round 5
// 1115.210 us; speedup vs baseline: 1.2570x; 1.0597x over previous
//
#include <hip/hip_runtime.h>
#include <cstdint>
#include <cstddef>

// ---------------------------------------------------------------------------
// QwenDoubleStreamAttention — round 8: double-buffered K/V LDS in attn
// (1 barrier per K-tile instead of 2).
//   B=2, S_img=2048, S_txt=256 (S=2304), D=3072, H=24, DH=128.
// Pipeline:
//   cvt_kernel       : hidden/enc fp32 -> bf16
//   transpose_w      : W fp32 [k][n] -> bf16 [n][k]
//   gemm_bf16<true>  : MFMA qkv proj -> bf16 [B][H][S][DH]
//   rmsrope_kernel   : RMSNorm + RoPE on q,k in place (q pre-scaled by DH^-0.5)
//   transpose_v      : V [B][H][S][DH] -> Vt [B][H][DH][S]
//   attn_kernel      : 512 thr / 8 waves / 256 q-rows; 32x32x16 swapped-QK^T
//                      flash attention, in-register softmax (cvt_pk +
//                      permlane32_swap), XOR-swizzled K/Vt LDS, DOUBLE-
//                      BUFFERED (64 KB, 2 blocks/CU) -> 1 barrier/tile,
//                      defer-max, counted-prefetch (loads kt+2 in flight),
//                      chunked XCD swizzle (grid 432 = 8 x 54).
//   gemm_bf16<false> : MFMA out-proj -> d_out fp32
// Workspace: 226,492,416 B (round-1 budget, proven available).
// ---------------------------------------------------------------------------

#define D_MODEL 3072
#define NHEADS 24
#define DHEAD 128
#define S_IMGC 2048
#define S_TXTC 256
#define S_TOT 2304
#define BATCH 2
#define ATT_SCALE 0.08838834764831845f  // 128^-0.5

typedef __attribute__((ext_vector_type(8))) short short8;   // 8 bf16 = 4 VGPR
typedef __attribute__((ext_vector_type(4))) float f32x4;
typedef __attribute__((ext_vector_type(16))) float f32x16;
typedef __attribute__((ext_vector_type(4))) unsigned int uint4v;

__device__ __forceinline__ ushort f2bf(float f) {  // fp32 -> bf16 RNE
    uint u = __float_as_uint(f);
    return (ushort)((u + 0x7fffu + ((u >> 16) & 1u)) >> 16);
}

__device__ __forceinline__ uint pk_bf16(float lo, float hi) {
    uint r;
    asm("v_cvt_pk_bf16_f32 %0, %1, %2" : "=v"(r) : "v"(lo), "v"(hi));
    return r;
}

// ---------------------------------------------------------------------------
__global__ __launch_bounds__(256) void cvt_kernel(
    const float* __restrict__ src, ushort* __restrict__ dst, int n4)
{
    int i = blockIdx.x * 256 + threadIdx.x;
    if (i >= n4) return;
    float4 v = ((const float4*)src)[i];
    ushort4 o;
    o.x = f2bf(v.x); o.y = f2bf(v.y); o.z = f2bf(v.z); o.w = f2bf(v.w);
    ((ushort4*)dst)[i] = o;
}

// ---------------------------------------------------------------------------
// W fp32 [k][n] -> bf16 [n][k].  64x64 LDS tile; grid.z picks weight.
// ---------------------------------------------------------------------------
__global__ __launch_bounds__(256) void transpose_w(
    const float* __restrict__ W0, const float* __restrict__ W1,
    const float* __restrict__ W2,
    ushort* __restrict__ T0, ushort* __restrict__ T1, ushort* __restrict__ T2)
{
    __shared__ float tile[64][68];
    const int z = blockIdx.z;
    const float* __restrict__ W = (z == 0) ? W0 : (z == 1) ? W1 : W2;
    ushort* __restrict__ T      = (z == 0) ? T0 : (z == 1) ? T1 : T2;
    const int tid = threadIdx.x;
    const int k0 = blockIdx.x * 64, n0 = blockIdx.y * 64;
    const int r = tid >> 4, c4 = (tid & 15) * 4;
#pragma unroll
    for (int i = 0; i < 4; i++) {
        float4 v = *(const float4*)(W + (size_t)(k0 + r + 16 * i) * D_MODEL + n0 + c4);
        *(float4*)&tile[r + 16 * i][c4] = v;
    }
    __syncthreads();
#pragma unroll
    for (int i = 0; i < 4; i++) {
        const int nn = n0 + r + 16 * i;
        ushort4 o;
        o.x = f2bf(tile[c4 + 0][r + 16 * i]);
        o.y = f2bf(tile[c4 + 1][r + 16 * i]);
        o.z = f2bf(tile[c4 + 2][r + 16 * i]);
        o.w = f2bf(tile[c4 + 3][r + 16 * i]);
        *(ushort4*)(T + (size_t)nn * D_MODEL + k0 + c4) = o;
    }
}

// ---------------------------------------------------------------------------
// V bf16 [B][H][S][DH] -> Vt bf16 [B][H][DH][S].  64x64 tiles.
// ---------------------------------------------------------------------------
__global__ __launch_bounds__(256) void transpose_v(
    const ushort* __restrict__ v, ushort* __restrict__ vt)
{
    __shared__ ushort t[64][72];
    const int bh = blockIdx.z;
    const int s0 = blockIdx.x * 64, d0 = blockIdx.y * 64;
    const size_t base  = (size_t)bh * S_TOT * DHEAD;
    const size_t baset = (size_t)bh * DHEAD * S_TOT;
    const int tid = threadIdx.x;
#pragma unroll
    for (int i = 0; i < 2; i++) {
        int id = tid + 256 * i;
        int r = id >> 3, c = (id & 7) * 8;
        *(uint4*)&t[r][c] = *(const uint4*)(v + base + (size_t)(s0 + r) * DHEAD + d0 + c);
    }
    __syncthreads();
#pragma unroll
    for (int i = 0; i < 2; i++) {
        int id = tid + 256 * i;
        int r = id >> 3, c = (id & 7) * 8;  // r = dh_loc, c = s chunk base
        ushort tmp[8];
#pragma unroll
        for (int j = 0; j < 8; j++) tmp[j] = t[c + j][r];
        *(uint4*)(vt + baset + (size_t)(d0 + r) * S_TOT + s0 + c) = *(uint4*)tmp;
    }
}

// ---------------------------------------------------------------------------
// MFMA GEMM (round-2 structure, unchanged).
// ---------------------------------------------------------------------------
template <bool QKV_STORE>
__global__ __launch_bounds__(256) void gemm_bf16(
    const ushort* __restrict__ A, size_t A_bstride, int As_off, int rows_per_b,
    const ushort* __restrict__ B0, const ushort* __restrict__ B1,
    const ushort* __restrict__ B2,
    const float* __restrict__ bi0, const float* __restrict__ bi1,
    const float* __restrict__ bi2,
    ushort* __restrict__ Q0, ushort* __restrict__ Q1, ushort* __restrict__ Q2,
    float* __restrict__ Cf, int C_s_off)
{
    __shared__ ushort As[128 * 32];
    __shared__ ushort Bs[128 * 32];

    const int z = blockIdx.z;
    const ushort* __restrict__ Wt  = (z == 0) ? B0 : (z == 1) ? B1 : B2;
    const float* __restrict__ bias = (z == 0) ? bi0 : (z == 1) ? bi1 : bi2;
    ushort* __restrict__ Cq        = (z == 0) ? Q0 : (z == 1) ? Q1 : Q2;

    const int tid = threadIdx.x;
    const int w = tid >> 6, lane = tid & 63;
    const int m0 = blockIdx.x * 128, n0 = blockIdx.y * 128;
    const int wm = w & 1, wn = w >> 1;

    const int ar0 = w * 32 + (lane >> 2);
    const int ar1 = ar0 + 16;
    const int acol = (lane & 3) * 8;
    const int ma0 = m0 + ar0, ma1 = m0 + ar1;
    const ushort* gA0 = A + (size_t)(ma0 / rows_per_b) * A_bstride +
                        (size_t)(ma0 % rows_per_b + As_off) * D_MODEL + acol;
    const ushort* gA1 = A + (size_t)(ma1 / rows_per_b) * A_bstride +
                        (size_t)(ma1 % rows_per_b + As_off) * D_MODEL + acol;
    const ushort* gB0 = Wt + (size_t)(n0 + ar0) * D_MODEL + acol;
    const ushort* gB1 = Wt + (size_t)(n0 + ar1) * D_MODEL + acol;
    ushort* lA0 = As + (w * 32) * 32;
    ushort* lA1 = As + (w * 32 + 16) * 32;
    ushort* lB0 = Bs + (w * 32) * 32;
    ushort* lB1 = Bs + (w * 32 + 16) * 32;

    f32x4 acc[4][4];
#pragma unroll
    for (int i = 0; i < 4; i++)
#pragma unroll
        for (int j = 0; j < 4; j++) acc[i][j] = (f32x4)0.f;

    const ushort* ap = As + (wm * 64 + (lane & 15)) * 32 + (lane >> 4) * 8;
    const ushort* bp = Bs + (wn * 64 + (lane & 15)) * 32 + (lane >> 4) * 8;

    for (int k0 = 0; k0 < D_MODEL; k0 += 32) {
        __syncthreads();
        __builtin_amdgcn_global_load_lds(
            (const __attribute__((address_space(1))) void*)(gA0 + k0),
            (__attribute__((address_space(3))) void*)lA0, 16, 0, 0);
        __builtin_amdgcn_global_load_lds(
            (const __attribute__((address_space(1))) void*)(gA1 + k0),
            (__attribute__((address_space(3))) void*)lA1, 16, 0, 0);
        __builtin_amdgcn_global_load_lds(
            (const __attribute__((address_space(1))) void*)(gB0 + k0),
            (__attribute__((address_space(3))) void*)lB0, 16, 0, 0);
        __builtin_amdgcn_global_load_lds(
            (const __attribute__((address_space(1))) void*)(gB1 + k0),
            (__attribute__((address_space(3))) void*)lB1, 16, 0, 0);
        __syncthreads();

        short8 af[4], bf[4];
#pragma unroll
        for (int mt = 0; mt < 4; mt++) af[mt] = *(const short8*)(ap + mt * 512);
#pragma unroll
        for (int nt = 0; nt < 4; nt++) bf[nt] = *(const short8*)(bp + nt * 512);
#pragma unroll
        for (int mt = 0; mt < 4; mt++)
#pragma unroll
            for (int nt = 0; nt < 4; nt++)
                acc[mt][nt] = __builtin_amdgcn_mfma_f32_16x16x32_bf16(
                    af[mt], bf[nt], acc[mt][nt], 0, 0, 0);
    }

    const int col_loc = wn * 64 + (lane & 15);
    const int row_base = m0 + wm * 64 + (lane >> 4) * 4;
    float bv[4];
#pragma unroll
    for (int nt = 0; nt < 4; nt++) bv[nt] = bias[n0 + col_loc + nt * 16];
#pragma unroll
    for (int mt = 0; mt < 4; mt++) {
#pragma unroll
        for (int r = 0; r < 4; r++) {
            const int mm = row_base + mt * 16 + r;
            if (QKV_STORE) {
                const int bb = mm / rows_per_b;
                const int s = mm - bb * rows_per_b + C_s_off;
                ushort* dst = Cq + (((size_t)bb * NHEADS + blockIdx.y) * S_TOT + s) * DHEAD;
#pragma unroll
                for (int nt = 0; nt < 4; nt++)
                    dst[col_loc + nt * 16] = f2bf(acc[mt][nt][r] + bv[nt]);
            } else {
                float* dst = Cf + (size_t)mm * D_MODEL + n0;
#pragma unroll
                for (int nt = 0; nt < 4; nt++)
                    dst[col_loc + nt * 16] = acc[mt][nt][r] + bv[nt];
            }
        }
    }
}

// ---------------------------------------------------------------------------
// RMSNorm + RoPE in place on bf16 q/k ([B][H][S][DH]).  Wave per row.
// q path additionally folds in ATT_SCALE (so attn skips the per-score mult).
// ---------------------------------------------------------------------------
__global__ __launch_bounds__(256) void rmsrope_kernel(
    ushort* __restrict__ qbuf, ushort* __restrict__ kbuf,
    const float* __restrict__ gq, const float* __restrict__ gk,
    const float* __restrict__ gqa, const float* __restrict__ gka,
    const float* __restrict__ icos, const float* __restrict__ isin,
    const float* __restrict__ tcos, const float* __restrict__ tsin)
{
    const int t = threadIdx.x & 63;
    const int row = blockIdx.x * 4 + (threadIdx.x >> 6);
    const int s = row % S_TOT;
    const bool is_img = s < S_IMGC;
    ushort* __restrict__ buf = blockIdx.y ? kbuf : qbuf;
    const float* __restrict__ g =
        blockIdx.y ? (is_img ? gk : gka) : (is_img ? gq : gqa);
    const int pos = is_img ? s : s - S_IMGC;
    const float* __restrict__ ct = (is_img ? icos : tcos) + pos * 64;
    const float* __restrict__ st = (is_img ? isin : tsin) + pos * 64;
    const float qs = blockIdx.y ? 1.0f : ATT_SCALE;

    ushort* p = buf + (size_t)row * DHEAD + t * 2;
    uint u = *(uint*)p;
    const float x0 = __uint_as_float(u << 16);
    const float x1 = __uint_as_float(u & 0xffff0000u);
    float ss = x0 * x0 + x1 * x1;
#pragma unroll
    for (int off = 1; off < 64; off <<= 1) ss += __shfl_xor(ss, off, 64);
    const float r = rsqrtf(ss * (1.0f / DHEAD) + 1e-5f);
    const float y0 = x0 * r * g[t * 2];
    const float y1 = x1 * r * g[t * 2 + 1];
    const float c = ct[t], sn = st[t];
    const float o0 = (y0 * c - y1 * sn) * qs;
    const float o1 = (y0 * sn + y1 * c) * qs;
    *(uint*)p = (uint)f2bf(o0) | ((uint)f2bf(o1) << 16);
}

// ---------------------------------------------------------------------------
// MFMA flash attention, m214 8-wave geometry + DOUBLE-BUFFERED K/V LDS.
// 512 threads = 8 waves, block owns 256 q-rows, K-tile = 64 keys.
// Per-wave inner math identical to the round-5/7 passing kernel:
//   swapped QK^T (mfma(K,Q)) -> lane-local P rows; in-register softmax;
//   P->PV frags via cvt_pk + permlane32_swap; XOR-swizzled K/Vt LDS;
//   defer-max; counted-prefetch (loads kt+2 issued before the barrier and
//   left in flight; their vmcnt is covered by a full tile's compute).
// Double-buffer protocol (1 barrier/tile):
//   iter kt: compute from buf[cur]; write tile kt+1 into buf[cur^1]
//   (no conflict with readers of buf[cur]); issue loads kt+2;
//   lgkmcnt(0)+s_barrier -> all waves' writes visible AND all reads of
//   buf[cur] retired (each wave's reads precede its own barrier); swap.
// LDS = 64 KB -> 2 blocks/CU (VGPR 108 -> 4 waves/SIMD).
// Grid: 1-D 432 with chunked XCD remap pid=(bid&7)*54+bid/8.
// ---------------------------------------------------------------------------
__global__ __launch_bounds__(512) void attn_kernel(
    const ushort* __restrict__ qb, const ushort* __restrict__ kb,
    const ushort* __restrict__ vtb, ushort* __restrict__ ob,
    const int* __restrict__ maskp)
{
    // per buffer: K (64x128 ushort, swizzled 256B rows) at +0 (16 KB),
    //             Vt (128x64 ushort, swizzled 128B rows) at +16384.
    __shared__ __align__(16) char smem[2][32768];

    // --- chunked XCD swizzle: 432 = 8 * 54; payload = (b,h,x) x-fastest
    const int bid = blockIdx.x;
    const int pid = (bid & 7) * 54 + (bid >> 3);
    const int x   = pid % 9;
    const int bh_ = pid / 9;          // 0..47
    const int h   = bh_ % 24;
    const int b   = bh_ / 24;
    const int q0  = x * 256;

    const int tid = threadIdx.x;
    const int w = tid >> 6, lane = tid & 63;
    const int l5 = lane & 31, hi = lane >> 5;
    const size_t hb  = ((size_t)b * NHEADS + h) * S_TOT * DHEAD;
    const size_t hbt = ((size_t)b * NHEADS + h) * DHEAD * S_TOT;
    const ushort* kp  = kb + hb;
    const ushort* vtp = vtb + hbt;
    const int NT = S_TOT / 64;  // 36

    char* curb = &smem[0][0];
    char* nxtb = &smem[1][0];

    // Q fragments (regs): B-operand, n = l5 (q row), k = hi*8+j per 16-dh step
    short8 qf[8];
#pragma unroll
    for (int ks = 0; ks < 8; ks++)
        qf[ks] = *(const short8*)(qb + hb +
            (size_t)(q0 + w * 32 + l5) * DHEAD + ks * 16 + hi * 8);

    f32x16 o_acc[4];
#pragma unroll
    for (int nt = 0; nt < 4; nt++) o_acc[nt] = (f32x16)0.f;
    float mrow = -1e30f, lrow = 0.f;

    // staging addresses (per thread, constant across tiles)
    const int kc = tid, krow = kc >> 4, kslot = kc & 15;
    const int kc2 = tid + 512, krow2 = kc2 >> 4, kslot2 = kc2 & 15;
    const int koff  = krow  * 256 + ((kslot  * 16) ^ ((krow  & 15) << 4));
    const int koff2 = krow2 * 256 + ((kslot2 * 16) ^ ((krow2 & 15) << 4));
    const int vrow = tid >> 3, vslot = tid & 7;
    const int vrow2 = (tid + 512) >> 3, vslot2 = (tid + 512) & 7;
    const int voff  = vrow  * 128 + ((vslot  * 16) ^ ((vrow  & 7) << 4));
    const int voff2 = vrow2 * 128 + ((vslot2 * 16) ^ ((vrow2 & 7) << 4));

    // ---- prologue: load tile 0, write to buf0, issue loads for tile 1
    uint4 kpre[2], vpre[2];
    kpre[0] = *(const uint4*)(kp + (size_t)krow * DHEAD + kslot * 8);
    kpre[1] = *(const uint4*)(kp + (size_t)krow2 * DHEAD + kslot2 * 8);
    vpre[0] = *(const uint4*)(vtp + (size_t)vrow * S_TOT + vslot * 8);
    vpre[1] = *(const uint4*)(vtp + (size_t)vrow2 * S_TOT + vslot2 * 8);
    *(uint4*)(curb + koff)          = kpre[0];
    *(uint4*)(curb + koff2)         = kpre[1];
    *(uint4*)(curb + 16384 + voff)  = vpre[0];
    *(uint4*)(curb + 16384 + voff2) = vpre[1];
    kpre[0] = *(const uint4*)(kp + (size_t)(64 + krow) * DHEAD + kslot * 8);
    kpre[1] = *(const uint4*)(kp + (size_t)(64 + krow2) * DHEAD + kslot2 * 8);
    vpre[0] = *(const uint4*)(vtp + (size_t)vrow * S_TOT + 64 + vslot * 8);
    vpre[1] = *(const uint4*)(vtp + (size_t)vrow2 * S_TOT + 64 + vslot2 * 8);
    asm volatile("s_waitcnt lgkmcnt(0)" ::: "memory");
    __builtin_amdgcn_sched_barrier(0);
    __builtin_amdgcn_s_barrier();   // tile 0 visible; tile-1 loads in flight

    for (int kt = 0; kt < NT; kt++) {
        const int k0 = kt * 64;
        const char* Kb = curb;
        const char* Vb = curb + 16384;

        // ---- S^T = K Q^T : two 32-key m-tiles, k over 128 dh
        f32x16 sa[2];
        sa[0] = (f32x16)0.f; sa[1] = (f32x16)0.f;
        __builtin_amdgcn_s_setprio(1);
#pragma unroll
        for (int ks = 0; ks < 8; ks++) {
#pragma unroll
            for (int mt = 0; mt < 2; mt++) {
                const int row = mt * 32 + l5;
                const short8 kfr = *(const short8*)(Kb + row * 256 +
                    ((ks * 32 + hi * 16) ^ ((row & 15) << 4)));
                sa[mt] = __builtin_amdgcn_mfma_f32_32x32x16_bf16(
                    kfr, qf[ks], sa[mt], 0, 0, 0);
            }
        }
        __builtin_amdgcn_s_setprio(0);

        // ---- mask (txt keys only; key = k0 + mt*32 + crow(r,hi))
        if (k0 >= S_IMGC) {
            const int kbase = b * S_TXTC + (k0 - S_IMGC) + 4 * hi;
#pragma unroll
            for (int mt = 0; mt < 2; mt++)
#pragma unroll
                for (int r = 0; r < 16; r++)
                    if (maskp[kbase + mt * 32 + (r & 3) + 8 * (r >> 2)] == 0)
                        sa[mt][r] = -1e9f;
        }

        // ---- online softmax: lane owns q = l5; lane+partner cover 64 keys
        float mx = sa[0][0];
#pragma unroll
        for (int r = 1; r < 16; r++) mx = fmaxf(mx, sa[0][r]);
#pragma unroll
        for (int r = 0; r < 16; r++) mx = fmaxf(mx, sa[1][r]);
        mx = fmaxf(mx, __shfl_xor(mx, 32, 64));

        if (!__all(mx <= mrow + 8.f)) {   // defer-max: rescale only on growth
            const float mn = fmaxf(mrow, mx);
            const float al = __expf(mrow - mn);
            mrow = mn;
            lrow *= al;
#pragma unroll
            for (int r = 0; r < 16; r++) {
                const float alr = __shfl(al, (r & 3) + 8 * (r >> 2) + 4 * hi, 64);
#pragma unroll
                for (int nt = 0; nt < 4; nt++) o_acc[nt][r] *= alr;
            }
        }
        float ps = 0.f;
#pragma unroll
        for (int mt = 0; mt < 2; mt++)
#pragma unroll
            for (int r = 0; r < 16; r++) {
                const float p = __expf(sa[mt][r] - mrow);
                sa[mt][r] = p;
                ps += p;
            }
        ps += __shfl_xor(ps, 32, 64);
        lrow += ps;

        // ---- P -> bf16 PV A-frags (in-register, cvt_pk + permlane32_swap)
        //      swap(LOWpair, HIpair): LOWpair.hi <-> HIpair.lo ->
        //      LOWpair_new = j01, HIpair_new = j45.
        short8 av[4];
#pragma unroll
        for (int ks = 0; ks < 4; ks++) {
            const int mt = ks >> 1, off = (ks & 1) * 8;
            uint B1 = pk_bf16(sa[mt][off + 0], sa[mt][off + 1]);
            uint A1 = pk_bf16(sa[mt][off + 4], sa[mt][off + 5]);
            uint B2 = pk_bf16(sa[mt][off + 2], sa[mt][off + 3]);
            uint A2 = pk_bf16(sa[mt][off + 6], sa[mt][off + 7]);
            asm volatile("v_permlane32_swap_b32 %0, %1" : "+v"(B1), "+v"(A1));
            asm volatile("v_permlane32_swap_b32 %0, %1" : "+v"(B2), "+v"(A2));
            union { uint4v u; short8 s; } cv;
            cv.u[0] = B1;  // j0,j1
            cv.u[1] = B2;  // j2,j3
            cv.u[2] = A1;  // j4,j5
            cv.u[3] = A2;  // j6,j7
            av[ks] = cv.s;
        }

        // ---- O += P V  (B = Vt rows, conflict-free swizzled b128)
        __builtin_amdgcn_s_setprio(1);
#pragma unroll
        for (int ks = 0; ks < 4; ks++) {
#pragma unroll
            for (int nt = 0; nt < 4; nt++) {
                const int row = nt * 32 + l5;
                const short8 vf = *(const short8*)(Vb + row * 128 +
                    ((ks * 32 + hi * 16) ^ ((row & 7) << 4)));
                o_acc[nt] = __builtin_amdgcn_mfma_f32_32x32x16_bf16(
                    av[ks], vf, o_acc[nt], 0, 0, 0);
            }
        }
        __builtin_amdgcn_s_setprio(0);

        // ---- double-buffer staging: write kt+1 into the idle buffer,
        //      issue loads kt+2, ONE barrier, swap.
        if (kt + 1 < NT) {
            *(uint4*)(nxtb + koff)          = kpre[0];   // vmcnt via reg-dep
            *(uint4*)(nxtb + koff2)         = kpre[1];
            *(uint4*)(nxtb + 16384 + voff)  = vpre[0];
            *(uint4*)(nxtb + 16384 + voff2) = vpre[1];
            if (kt + 2 < NT) {              // issue loads kt+2, left in flight
                const int k0n = (kt + 2) * 64;
                kpre[0] = *(const uint4*)(kp + (size_t)(k0n + krow) * DHEAD + kslot * 8);
                kpre[1] = *(const uint4*)(kp + (size_t)(k0n + krow2) * DHEAD + kslot2 * 8);
                vpre[0] = *(const uint4*)(vtp + (size_t)vrow * S_TOT + k0n + vslot * 8);
                vpre[1] = *(const uint4*)(vtp + (size_t)vrow2 * S_TOT + k0n + vslot2 * 8);
            }
            asm volatile("s_waitcnt lgkmcnt(0)" ::: "memory");
            __builtin_amdgcn_sched_barrier(0);
            __builtin_amdgcn_s_barrier();   // kt+1 visible; kt+2 loads in flight
            char* t = curb; curb = nxtb; nxtb = t;
        }
    }

    // ---- epilogue: normalize, write bf16 O as [B][S][H*DH]
    const float linv = 1.0f / lrow;
#pragma unroll
    for (int r = 0; r < 16; r++) {
        const int crow = (r & 3) + 8 * (r >> 2) + 4 * hi;
        const float lr = __shfl(linv, crow, 64);
        const int s = q0 + w * 32 + crow;
        ushort* dst = ob + ((size_t)b * S_TOT + s) * D_MODEL + h * DHEAD + l5;
#pragma unroll
        for (int nt = 0; nt < 4; nt++)
            dst[nt * 32] = f2bf(o_acc[nt][r] * lr);
    }
}

// ---------------------------------------------------------------------------
extern "C" void kernel_launch(void* const* d_in, const int* in_sizes, int n_in,
                              void* d_out, int out_size, void* d_ws, size_t ws_size,
                              hipStream_t stream)
{
    const float* hidden = (const float*)d_in[0];
    const float* enc    = (const float*)d_in[1];
    const int* encmask  = (const int*)d_in[2];
    const float* icos = (const float*)d_in[4];
    const float* isin = (const float*)d_in[5];
    const float* tcos = (const float*)d_in[6];
    const float* tsin = (const float*)d_in[7];
    const float* wq  = (const float*)d_in[8];  const float* bq  = (const float*)d_in[9];
    const float* wk  = (const float*)d_in[10]; const float* bk  = (const float*)d_in[11];
    const float* wv  = (const float*)d_in[12]; const float* bv  = (const float*)d_in[13];
    const float* wqa = (const float*)d_in[14]; const float* bqa = (const float*)d_in[15];
    const float* wka = (const float*)d_in[16]; const float* bka = (const float*)d_in[17];
    const float* wva = (const float*)d_in[18]; const float* bva = (const float*)d_in[19];
    const float* wo  = (const float*)d_in[20]; const float* bo  = (const float*)d_in[21];
    const float* woa = (const float*)d_in[22]; const float* boa = (const float*)d_in[23];
    const float* gq  = (const float*)d_in[24]; const float* gk  = (const float*)d_in[25];
    const float* gqa = (const float*)d_in[26]; const float* gka = (const float*)d_in[27];
    float* out = (float*)d_out;

    const size_t W_ELE = (size_t)D_MODEL * D_MODEL;
    const size_t NQKV  = (size_t)BATCH * NHEADS * S_TOT * DHEAD;
    char* p = (char*)d_ws;
    ushort* wT0 = (ushort*)p; p += W_ELE * 2;
    ushort* wT1 = (ushort*)p; p += W_ELE * 2;
    ushort* wT2 = (ushort*)p; p += W_ELE * 2;
    ushort* ximg = (ushort*)p; p += (size_t)BATCH * S_IMGC * D_MODEL * 2;
    ushort* xtxt = (ushort*)p; p += (size_t)BATCH * S_TXTC * D_MODEL * 2;
    ushort* qbuf = (ushort*)p; p += NQKV * 2;
    ushort* kbuf = (ushort*)p; p += NQKV * 2;
    ushort* vbuf = (ushort*)p; p += NQKV * 2;
    ushort* vtbuf = (ushort*)p; p += NQKV * 2;
    ushort* obuf = (ushort*)p; p += (size_t)BATCH * S_TOT * D_MODEL * 2;
    if ((size_t)(p - (char*)d_ws) > ws_size) return;  // 226.5 MB needed

    const dim3 blk(256);

    cvt_kernel<<<dim3((BATCH * S_IMGC * D_MODEL / 4 + 255) / 256), blk, 0, stream>>>(
        hidden, ximg, BATCH * S_IMGC * D_MODEL / 4);
    cvt_kernel<<<dim3((BATCH * S_TXTC * D_MODEL / 4 + 255) / 256), blk, 0, stream>>>(
        enc, xtxt, BATCH * S_TXTC * D_MODEL / 4);

    transpose_w<<<dim3(48, 48, 3), blk, 0, stream>>>(wq, wk, wv, wT0, wT1, wT2);
    gemm_bf16<true><<<dim3(32, 24, 3), blk, 0, stream>>>(
        ximg, (size_t)S_IMGC * D_MODEL, 0, S_IMGC,
        wT0, wT1, wT2, bq, bk, bv, qbuf, kbuf, vbuf, nullptr, 0);
    transpose_w<<<dim3(48, 48, 3), blk, 0, stream>>>(wqa, wka, wva, wT0, wT1, wT2);
    gemm_bf16<true><<<dim3(4, 24, 3), blk, 0, stream>>>(
        xtxt, (size_t)S_TXTC * D_MODEL, 0, S_TXTC,
        wT0, wT1, wT2, bqa, bka, bva, qbuf, kbuf, vbuf, nullptr, S_IMGC);

    rmsrope_kernel<<<dim3(BATCH * NHEADS * S_TOT / 4, 2), blk, 0, stream>>>(
        qbuf, kbuf, gq, gk, gqa, gka, icos, isin, tcos, tsin);

    transpose_v<<<dim3(S_TOT / 64, DHEAD / 64, BATCH * NHEADS), blk, 0, stream>>>(
        vbuf, vtbuf);

    attn_kernel<<<dim3(432), dim3(512), 0, stream>>>(
        qbuf, kbuf, vtbuf, obuf, encmask);

    transpose_w<<<dim3(48, 48, 1), blk, 0, stream>>>(wo, wo, wo, wT0, wT0, wT0);
    gemm_bf16<false><<<dim3(32, 24, 1), blk, 0, stream>>>(
        obuf, (size_t)S_TOT * D_MODEL, 0, S_IMGC,
        wT0, wT0, wT0, bo, bo, bo, nullptr, nullptr, nullptr, out, 0);
    transpose_w<<<dim3(48, 48, 1), blk, 0, stream>>>(woa, woa, woa, wT0, wT0, wT0);
    gemm_bf16<false><<<dim3(4, 24, 1), blk, 0, stream>>>(
        obuf, (size_t)S_TOT * D_MODEL, S_IMGC, S_TXTC,
        wT0, wT0, wT0, boa, boa, boa, nullptr, nullptr, nullptr,
        out + (size_t)BATCH * S_IMGC * D_MODEL, 0);
}